// Round 10
// baseline (114.192 us; speedup 1.0000x reference)
//
#include <hip/hip_runtime.h>

#define B_TOT 1024   // BATCH * nbr = 64 * 16
#define L_DIM 64
#define K_DIM 32
#define OUT_K 32
#define EPS_BN 1e-5f

__device__ __forceinline__ float reduce64(float v) {
    #pragma unroll
    for (int w = 1; w < 64; w <<= 1) v += __shfl_xor(v, w);
    return v;
}

// ---------------------------------------------------------------------------
// Kernel 1: Hmk[b,c,l] = mean_k H[b,c,l,k], Hml[b,c,k] = mean_l H[b,c,l,k]
// where H[b, ri*4+u, l, k] = Hhat_{ri}[b, l, k, u]. FUSED with layer-0:
// A0_ap = relu(0.1*P0a@Hmk), A0_ue = relu(0.1*P0u@Hml) computed in-register
// (never stored); only BN stats (sum/sumsq) are emitted to muS/muQ.
// LDS tile stride padded to 132 words to break column-sum bank conflicts.
// ---------------------------------------------------------------------------
__global__ __launch_bounds__(256, 4) void hmeans_l0_kernel(
    const float* __restrict__ Hr, const float* __restrict__ Hi,
    float* __restrict__ Hmk, float* __restrict__ Hml,
    const float* __restrict__ P0,   // layer0: P1a | P1u
    float* __restrict__ muS, float* __restrict__ muQ) {
    __shared__ float tile[64 * 132];
    __shared__ float hmkS[512];  // [c][l]
    __shared__ float hmlS[256];  // [c][k]
    int b = blockIdx.x;
    int tid = threadIdx.x;
    for (int ri = 0; ri < 2; ++ri) {
        const float* src = (ri == 0 ? Hr : Hi) + (size_t)b * 8192;
        const float4* src4 = (const float4*)src;
        for (int j = tid; j < 2048; j += 256) {
            float4 v = src4[j];
            int l = j >> 5, w0 = (j & 31) * 4;
            float* d = &tile[l * 132 + w0];
            d[0] = v.x; d[1] = v.y; d[2] = v.z; d[3] = v.w;
        }
        __syncthreads();
        {
            int l = tid >> 2, u = tid & 3;
            float s = 0.f;
            #pragma unroll
            for (int kk = 0; kk < 32; ++kk) s += tile[l * 132 + kk * 4 + u];
            s *= (1.0f / 32.0f);
            Hmk[(size_t)b * 512 + (ri * 4 + u) * 64 + l] = s;
            hmkS[(ri * 4 + u) * 64 + l] = s;
        }
        if (tid < 128) {
            int kk = tid >> 2, u = tid & 3;
            float s = 0.f;
            #pragma unroll
            for (int l = 0; l < 64; ++l) s += tile[l * 132 + kk * 4 + u];
            s *= (1.0f / 64.0f);
            Hml[(size_t)b * 256 + (ri * 4 + u) * 32 + kk] = s;
            hmlS[(ri * 4 + u) * 32 + kk] = s;
        }
        __syncthreads();
    }

    // ---- layer-0 stats (A0 never materialized) ----
    int wid = tid >> 6, lane = tid & 63;
    int o0 = __builtin_amdgcn_readfirstlane(wid << 4);
    float hmk[8], hml[8];
    #pragma unroll
    for (int c = 0; c < 8; ++c) hmk[c] = hmkS[c * 64 + lane];
    #pragma unroll
    for (int c = 0; c < 8; ++c) hml[c] = hmlS[c * 32 + (lane & 31)];

    // AP channels o0..o0+15 (2 batches of 8)
    for (int h = 0; h < 2; ++h) {
        float vs[8], qs[8];
        #pragma unroll
        for (int mm = 0; mm < 8; ++mm) {
            int o = o0 + h * 8 + mm;
            float4 p0 = *(const float4*)(P0 + o * 8);
            float4 p1 = *(const float4*)(P0 + o * 8 + 4);
            float pa = p0.x * hmk[0] + p0.y * hmk[1] + p0.z * hmk[2] + p0.w * hmk[3]
                     + p1.x * hmk[4] + p1.y * hmk[5] + p1.z * hmk[6] + p1.w * hmk[7];
            float v = fmaxf(0.1f * pa, 0.f);
            vs[mm] = v; qs[mm] = v * v;
        }
        #pragma unroll
        for (int s = 1; s < 64; s <<= 1) {
            #pragma unroll
            for (int mm = 0; mm < 8; ++mm) {
                vs[mm] += __shfl_xor(vs[mm], s);
                qs[mm] += __shfl_xor(qs[mm], s);
            }
        }
        if (lane == 0) {
            #pragma unroll
            for (int mm = 0; mm < 8; ++mm) {
                muS[b * 128 + o0 + h * 8 + mm] = vs[mm];
                muQ[b * 128 + o0 + h * 8 + mm] = qs[mm];
            }
        }
    }
    // UE channels o0..o0+15 (duplicated halves -> x0.5)
    for (int h = 0; h < 2; ++h) {
        float vs[8], qs[8];
        #pragma unroll
        for (int mm = 0; mm < 8; ++mm) {
            int o = o0 + h * 8 + mm;
            float4 p0 = *(const float4*)(P0 + 512 + o * 8);
            float4 p1 = *(const float4*)(P0 + 512 + o * 8 + 4);
            float pu = p0.x * hml[0] + p0.y * hml[1] + p0.z * hml[2] + p0.w * hml[3]
                     + p1.x * hml[4] + p1.y * hml[5] + p1.z * hml[6] + p1.w * hml[7];
            float v = fmaxf(0.1f * pu, 0.f);
            vs[mm] = v; qs[mm] = v * v;
        }
        #pragma unroll
        for (int s = 1; s < 64; s <<= 1) {
            #pragma unroll
            for (int mm = 0; mm < 8; ++mm) {
                vs[mm] += __shfl_xor(vs[mm], s);
                qs[mm] += __shfl_xor(qs[mm], s);
            }
        }
        if (lane == 0) {
            #pragma unroll
            for (int mm = 0; mm < 8; ++mm) {
                muS[b * 128 + 64 + o0 + h * 8 + mm] = vs[mm] * 0.5f;
                muQ[b * 128 + 64 + o0 + h * 8 + mm] = qs[mm] * 0.5f;
            }
        }
    }
}

// ---------------------------------------------------------------------------
// Q transpose: QT1a[i*64+o], QT1u[4096 + i*64+o] (layer-1 hidden mats),
// QT1o[8192 + i*32+o] (out layer). One block; tiny.
// ---------------------------------------------------------------------------
__global__ __launch_bounds__(256) void transpose_q_kernel(
    const float* __restrict__ Qh2,  // layer-1 Q base (Q1a|Q2a|Q1u|Q2u)
    const float* __restrict__ Qo,   // out-layer Q base (Q1o|Q2o)
    float* __restrict__ QT) {
    int t = threadIdx.x;
    const float* Q1a = Qh2;
    const float* Q1u = Qh2 + 2 * 4096;
    for (int idx = t; idx < 4096; idx += 256) {
        int i = idx >> 6, o = idx & 63;
        QT[idx]        = Q1a[o * 64 + i];
        QT[4096 + idx] = Q1u[o * 64 + i];
    }
    for (int idx = t; idx < 2048; idx += 256) {
        int i = idx >> 5, o = idx & 31;
        QT[8192 + idx] = Qo[o * 64 + i];
    }
}

// ---------------------------------------------------------------------------
// Hidden layer 1. Grid 2048: blocks [0,1024)=AP (b=blockIdx),
// [1024,2048)=UE (b=blockIdx-1024); scalar split -> uniform CF.
// A0 is RECOMPUTED per i from Hmk/Hml + P0 rows (8 FMAs, wave-uniform
// s_loads) with BN coefA folded — no global activation read exists.
// GEMM is i-major into acc[16] via QT (no per-output scalar-wait chains).
// Cross-term 2*Q2@mean(BN(A0)) precomputed per (b,o) in biasIn.
// Stats of output -> muS/muQ (batched butterflies).
// ---------------------------------------------------------------------------
__global__ __launch_bounds__(256, 4) void layer_hidden1_kernel(
    float* __restrict__ Aap_out,
    const float* __restrict__ Hmk, const float* __restrict__ Hml,
    const float* __restrict__ QT,   // QT1a | QT1u, i-major
    const float* __restrict__ P0,   // layer0 P1a | P1u
    const float* __restrict__ P1,   // layer1 P1a | P1u
    const float* __restrict__ coefIn, // scAP[64] shAP[64] scUE[64] shUE[64]
    const float* __restrict__ biasIn, // [b][128]
    float* __restrict__ muS, float* __restrict__ muQ) {
    int bb = blockIdx.x, tid = threadIdx.x;
    int wid = tid >> 6, lane = tid & 63;
    int o0 = __builtin_amdgcn_readfirstlane(wid << 4);

    if (bb < B_TOT) {
        // ------------------- AP path: lane = l -------------------
        int b = bb;
        float hmk[8];
        #pragma unroll
        for (int c = 0; c < 8; ++c) hmk[c] = Hmk[(size_t)b * 512 + c * 64 + lane];

        float bp[16];
        #pragma unroll
        for (int mm = 0; mm < 16; ++mm) {
            int o = o0 + mm;
            float4 p0 = *(const float4*)(P1 + o * 8);
            float4 p1 = *(const float4*)(P1 + o * 8 + 4);
            float pa = p0.x * hmk[0] + p0.y * hmk[1] + p0.z * hmk[2] + p0.w * hmk[3]
                     + p1.x * hmk[4] + p1.y * hmk[5] + p1.z * hmk[6] + p1.w * hmk[7];
            bp[mm] = 0.1f * pa + biasIn[b * 128 + o];
        }

        float acc[16];
        #pragma unroll
        for (int mm = 0; mm < 16; ++mm) acc[mm] = 0.f;
        #pragma unroll 4
        for (int i = 0; i < 64; ++i) {
            float4 pp0 = *(const float4*)(P0 + i * 8);
            float4 pp1 = *(const float4*)(P0 + i * 8 + 4);
            float a0 = pp0.x * hmk[0] + pp0.y * hmk[1] + pp0.z * hmk[2] + pp0.w * hmk[3]
                     + pp1.x * hmk[4] + pp1.y * hmk[5] + pp1.z * hmk[6] + pp1.w * hmk[7];
            float aa = fmaxf(0.1f * a0, 0.f) * coefIn[i] + coefIn[64 + i];
            float4 q0 = *(const float4*)(QT + i * 64 + o0);
            float4 q1 = *(const float4*)(QT + i * 64 + o0 + 4);
            float4 q2 = *(const float4*)(QT + i * 64 + o0 + 8);
            float4 q3 = *(const float4*)(QT + i * 64 + o0 + 12);
            acc[0]  += q0.x * aa; acc[1]  += q0.y * aa;
            acc[2]  += q0.z * aa; acc[3]  += q0.w * aa;
            acc[4]  += q1.x * aa; acc[5]  += q1.y * aa;
            acc[6]  += q1.z * aa; acc[7]  += q1.w * aa;
            acc[8]  += q2.x * aa; acc[9]  += q2.y * aa;
            acc[10] += q2.z * aa; acc[11] += q2.w * aa;
            acc[12] += q3.x * aa; acc[13] += q3.y * aa;
            acc[14] += q3.z * aa; acc[15] += q3.w * aa;
        }

        float vs[16], qs[16];
        #pragma unroll
        for (int mm = 0; mm < 16; ++mm) {
            float v = fmaxf(2.f * acc[mm] + bp[mm], 0.f);
            Aap_out[(size_t)b * 4096 + (o0 + mm) * 64 + lane] = v;
            vs[mm] = v; qs[mm] = v * v;
        }
        #pragma unroll
        for (int s = 1; s < 64; s <<= 1) {
            #pragma unroll
            for (int mm = 0; mm < 16; ++mm) {
                vs[mm] += __shfl_xor(vs[mm], s);
                qs[mm] += __shfl_xor(qs[mm], s);
            }
        }
        if (lane == 0) {
            #pragma unroll
            for (int mm = 0; mm < 16; ++mm) {
                muS[b * 128 + o0 + mm] = vs[mm];
                muQ[b * 128 + o0 + mm] = qs[mm];
            }
        }
    } else {
        // ------------------- UE path: lane = k (duplicated halves) ----------
        int b = bb - B_TOT;
        int k = lane & 31;
        float hml[8];
        #pragma unroll
        for (int c = 0; c < 8; ++c) hml[c] = Hml[(size_t)b * 256 + c * 32 + k];

        float bp[16];
        #pragma unroll
        for (int mm = 0; mm < 16; ++mm) {
            int o = o0 + mm;
            float4 p0 = *(const float4*)(P1 + 512 + o * 8);
            float4 p1 = *(const float4*)(P1 + 512 + o * 8 + 4);
            float pu = p0.x * hml[0] + p0.y * hml[1] + p0.z * hml[2] + p0.w * hml[3]
                     + p1.x * hml[4] + p1.y * hml[5] + p1.z * hml[6] + p1.w * hml[7];
            bp[mm] = 0.1f * pu + biasIn[b * 128 + 64 + o];
        }

        float acc[16];
        #pragma unroll
        for (int mm = 0; mm < 16; ++mm) acc[mm] = 0.f;
        const float* QTu = QT + 4096;
        #pragma unroll 4
        for (int i = 0; i < 64; ++i) {
            float4 pp0 = *(const float4*)(P0 + 512 + i * 8);
            float4 pp1 = *(const float4*)(P0 + 512 + i * 8 + 4);
            float a0 = pp0.x * hml[0] + pp0.y * hml[1] + pp0.z * hml[2] + pp0.w * hml[3]
                     + pp1.x * hml[4] + pp1.y * hml[5] + pp1.z * hml[6] + pp1.w * hml[7];
            float aa = fmaxf(0.1f * a0, 0.f) * coefIn[128 + i] + coefIn[192 + i];
            float4 q0 = *(const float4*)(QTu + i * 64 + o0);
            float4 q1 = *(const float4*)(QTu + i * 64 + o0 + 4);
            float4 q2 = *(const float4*)(QTu + i * 64 + o0 + 8);
            float4 q3 = *(const float4*)(QTu + i * 64 + o0 + 12);
            acc[0]  += q0.x * aa; acc[1]  += q0.y * aa;
            acc[2]  += q0.z * aa; acc[3]  += q0.w * aa;
            acc[4]  += q1.x * aa; acc[5]  += q1.y * aa;
            acc[6]  += q1.z * aa; acc[7]  += q1.w * aa;
            acc[8]  += q2.x * aa; acc[9]  += q2.y * aa;
            acc[10] += q2.z * aa; acc[11] += q2.w * aa;
            acc[12] += q3.x * aa; acc[13] += q3.y * aa;
            acc[14] += q3.z * aa; acc[15] += q3.w * aa;
        }

        float vs[16], qs[16];
        #pragma unroll
        for (int mm = 0; mm < 16; ++mm) {
            float v = fmaxf(2.f * acc[mm] + bp[mm], 0.f);
            vs[mm] = v; qs[mm] = v * v;
        }
        #pragma unroll
        for (int s = 1; s < 64; s <<= 1) {
            #pragma unroll
            for (int mm = 0; mm < 16; ++mm) {
                vs[mm] += __shfl_xor(vs[mm], s);
                qs[mm] += __shfl_xor(qs[mm], s);
            }
        }
        if (lane == 0) {
            #pragma unroll
            for (int mm = 0; mm < 16; ++mm) {
                muS[b * 128 + 64 + o0 + mm] = vs[mm] * 0.5f;
                muQ[b * 128 + 64 + o0 + mm] = qs[mm] * 0.5f;
            }
        }
    }
}

// ---------------------------------------------------------------------------
// BN finalize: block per channel (128). Reduces per-b raw sums (b-major),
// computes scale/shift: coef = scAP[64] shAP[64] scUE[64] shUE[64]
// ---------------------------------------------------------------------------
__global__ __launch_bounds__(256, 8) void bn_finalize_kernel(
    const float* __restrict__ muS, const float* __restrict__ muQ,
    const float* __restrict__ gamma, const float* __restrict__ beta,
    float* __restrict__ coef) {
    __shared__ float redS[4], redQ[4];
    int ch = blockIdx.x;   // 0..127
    int tid = threadIdx.x;
    float s = 0.f, q = 0.f;
    for (int j = tid; j < 1024; j += 256) {
        s += muS[j * 128 + ch];
        q += muQ[j * 128 + ch];
    }
    s = reduce64(s);
    q = reduce64(q);
    int wave = tid >> 6, lane = tid & 63;
    if (lane == 0) { redS[wave] = s; redQ[wave] = q; }
    __syncthreads();
    if (tid == 0) {
        s = redS[0] + redS[1] + redS[2] + redS[3];
        q = redQ[0] + redQ[1] + redQ[2] + redQ[3];
        bool ap = ch < 64;
        int o = ap ? ch : ch - 64;
        float cnt = ap ? (float)(B_TOT * L_DIM) : (float)(B_TOT * K_DIM);
        float m = s / cnt;
        float var = q / cnt - m * m;
        float sc = gamma[o] / sqrtf(var + EPS_BN);
        if (ap) { coef[o] = sc;       coef[64 + o] = beta[o] - m * sc; }
        else    { coef[128 + o] = sc; coef[192 + o] = beta[o] - m * sc; }
    }
}

// ---------------------------------------------------------------------------
// Hidden-layer bias precompute: bias[b][o]    = 2*Q2a[o,:]@muUE_bn[b,:]
//                               bias[b][64+o] = 2*Q2u[o,:]@muAP_bn[b,:]
// (linearity of BN over spatial mean). Q = consuming layer's Q base.
// ---------------------------------------------------------------------------
__global__ __launch_bounds__(128, 8) void bias_hidden_kernel(
    const float* __restrict__ Q, const float* __restrict__ coef,
    const float* __restrict__ muS, float* __restrict__ bias) {
    __shared__ float mubn[128];
    int b = blockIdx.x, t = threadIdx.x;
    float raw = muS[b * 128 + t];
    if (t < 64) mubn[t] = raw * (1.0f / 64.0f) * coef[t] + coef[64 + t];
    else        mubn[t] = raw * (1.0f / 32.0f) * coef[64 + t] + coef[128 + t];
    __syncthreads();
    const float* Qm = (t < 64) ? (Q + 4096) : (Q + 3 * 4096);
    const float* mu = (t < 64) ? (mubn + 64) : mubn;
    int o = t & 63;
    const float4* Qrow = (const float4*)(Qm + o * 64);
    float sa = 0.f, sb = 0.f, sc2 = 0.f, sd = 0.f;
    #pragma unroll
    for (int j = 0; j < 16; ++j) {
        float4 q = Qrow[j];
        sa += q.x * mu[4 * j];
        sb += q.y * mu[4 * j + 1];
        sc2 += q.z * mu[4 * j + 2];
        sd += q.w * mu[4 * j + 3];
    }
    bias[b * 128 + t] = 2.f * ((sa + sb) + (sc2 + sd));
}

// ---------------------------------------------------------------------------
// Output-layer bias: biasO[b][o] = 2*Q2o[o,:]@muUE_bn[b,:], o<32.
// ---------------------------------------------------------------------------
__global__ __launch_bounds__(64, 8) void bias_out_kernel(
    const float* __restrict__ Qo, const float* __restrict__ coef,
    const float* __restrict__ muS, float* __restrict__ biasO) {
    __shared__ float mubn[64];
    int b = blockIdx.x, t = threadIdx.x;
    mubn[t] = muS[b * 128 + 64 + t] * (1.0f / 32.0f) * coef[128 + t] + coef[192 + t];
    __syncthreads();
    if (t < 32) {
        const float4* Qrow = (const float4*)(Qo + OUT_K * 64 + t * 64);
        float sa = 0.f, sb = 0.f, sc2 = 0.f, sd = 0.f;
        #pragma unroll
        for (int j = 0; j < 16; ++j) {
            float4 q = Qrow[j];
            sa += q.x * mubn[4 * j];
            sb += q.y * mubn[4 * j + 1];
            sc2 += q.z * mubn[4 * j + 2];
            sd += q.w * mubn[4 * j + 3];
        }
        biasO[b * 32 + t] = 2.f * ((sa + sb) + (sc2 + sd));
    }
}

// ---------------------------------------------------------------------------
// Output layer fused with normalization/scale. i-major GEMM (QT1o at +8192).
// V[o][l] -> LDS; inv[k] = sqrt(L)/||V[k,:]||; Fhat = Vhat * V[k][l]*inv[k].
// ---------------------------------------------------------------------------
__global__ __launch_bounds__(256, 4) void layer_out_fin_kernel(
    const float* __restrict__ Aap_in,
    const float* __restrict__ Hmk,
    const float* __restrict__ QT,
    const float* __restrict__ Po,
    const float* __restrict__ coefIn,
    const float* __restrict__ biasO,
    const float* __restrict__ Vhat,
    float* __restrict__ out) {
    __shared__ float sV[32 * 65];
    __shared__ float inv[32];
    int b = blockIdx.x, tid = threadIdx.x;
    int wid = tid >> 6, lane = tid & 63;
    int ob = __builtin_amdgcn_readfirstlane(wid << 3);

    float hmk[8];
    #pragma unroll
    for (int c = 0; c < 8; ++c) hmk[c] = Hmk[(size_t)b * 512 + c * 64 + lane];

    float bp[8];
    #pragma unroll
    for (int m = 0; m < 8; ++m) {
        int o = ob + m;
        float4 p0 = *(const float4*)(Po + o * 8);
        float4 p1 = *(const float4*)(Po + o * 8 + 4);
        float pa = p0.x * hmk[0] + p0.y * hmk[1] + p0.z * hmk[2] + p0.w * hmk[3]
                 + p1.x * hmk[4] + p1.y * hmk[5] + p1.z * hmk[6] + p1.w * hmk[7];
        bp[m] = 0.1f * pa + biasO[b * 32 + o];
    }

    float acc[8];
    #pragma unroll
    for (int m = 0; m < 8; ++m) acc[m] = 0.f;
    {
        const float* A_in = Aap_in + (size_t)b * 4096 + lane;
        const float* QTo = QT + 8192;
        #pragma unroll 4
        for (int i = 0; i < 64; ++i) {
            float x = A_in[i * 64];
            float aa = x * coefIn[i] + coefIn[64 + i];
            float4 q0 = *(const float4*)(QTo + i * 32 + ob);
            float4 q1 = *(const float4*)(QTo + i * 32 + ob + 4);
            acc[0] += q0.x * aa; acc[1] += q0.y * aa;
            acc[2] += q0.z * aa; acc[3] += q0.w * aa;
            acc[4] += q1.x * aa; acc[5] += q1.y * aa;
            acc[6] += q1.z * aa; acc[7] += q1.w * aa;
        }
    }
    #pragma unroll
    for (int m = 0; m < 8; ++m)
        sV[(ob + m) * 65 + lane] = 2.f * acc[m] + bp[m];

    __syncthreads();
    if (tid < 32) {
        float s = 0.f;
        #pragma unroll
        for (int l = 0; l < 64; ++l) { float x = sV[tid * 65 + l]; s += x * x; }
        inv[tid] = 8.0f / sqrtf(s); // sqrt(L)=8
    }
    __syncthreads();
    const float4* vh4 = (const float4*)(Vhat + (size_t)b * 8192);
    float4* o4 = (float4*)out + (size_t)b * 2048;
    for (int j = tid; j < 2048; j += 256) {
        int l = j >> 5, kk = j & 31;
        float p = sV[kk * 65 + l] * inv[kk];
        float4 x = vh4[j];
        x.x *= p; x.y *= p; x.z *= p; x.w *= p;
        o4[j] = x;
    }
}

// ---------------------------------------------------------------------------
extern "C" void kernel_launch(void* const* d_in, const int* in_sizes, int n_in,
                              void* d_out, int out_size, void* d_ws, size_t ws_size,
                              hipStream_t stream) {
    const float* Hr        = (const float*)d_in[0];
    const float* Hi        = (const float*)d_in[1];
    const float* Vhat      = (const float*)d_in[2];
    const float* Qs_hidden = (const float*)d_in[3];
    const float* Ps_hidden = (const float*)d_in[4];
    const float* Qs_out    = (const float*)d_in[5];
    const float* Ps_out    = (const float*)d_in[6];
    const float* bn_gamma  = (const float*)d_in[7];
    const float* bn_beta   = (const float*)d_in[8];
    float* out = (float*)d_out;

    float* ws    = (float*)d_ws;
    float* Hmk   = ws;                    // 1024*512
    float* Hml   = Hmk + 524288;          // 1024*256
    float* AapB  = Hml + 262144;          // 1024*4096
    float* muS   = AapB + 4194304;        // 1024*128
    float* muQ   = muS + 131072;          // 1024*128
    float* coefA = muQ + 131072;          // 256
    float* coefB = coefA + 256;           // 256
    float* biasA = coefB + 256;           // 1024*128
    float* biasO = biasA + 131072;        // 1024*32
    float* QT    = biasO + 32768;         // 4096 + 4096 + 2048

    // Q transposes (reads inputs only)
    hipLaunchKernelGGL(transpose_q_kernel, dim3(1), dim3(256), 0, stream,
                       Qs_hidden + 4 * 4096, Qs_out, QT);

    // hmeans + layer-0 stats (A0 never materialized)
    hipLaunchKernelGGL(hmeans_l0_kernel, dim3(B_TOT), dim3(256), 0, stream,
                       Hr, Hi, Hmk, Hml, Ps_hidden, muS, muQ);
    hipLaunchKernelGGL(bn_finalize_kernel, dim3(128), dim3(256), 0, stream,
                       muS, muQ, bn_gamma, bn_beta, coefA);
    hipLaunchKernelGGL(bias_hidden_kernel, dim3(B_TOT), dim3(128), 0, stream,
                       Qs_hidden + 4 * 4096, coefA, muS, biasA);

    // hidden layer 1 (recomputes A0 from Hmk/Hml; BN fold coefA; bias biasA)
    hipLaunchKernelGGL(layer_hidden1_kernel, dim3(2 * B_TOT), dim3(256), 0, stream,
                       AapB, Hmk, Hml, QT,
                       Ps_hidden, Ps_hidden + 2 * 512,
                       coefA, biasA, muS, muQ);
    hipLaunchKernelGGL(bn_finalize_kernel, dim3(128), dim3(256), 0, stream,
                       muS, muQ, bn_gamma + 64, bn_beta + 64, coefB);
    hipLaunchKernelGGL(bias_out_kernel, dim3(B_TOT), dim3(64), 0, stream,
                       Qs_out, coefB, muS, biasO);

    // output layer fused with normalization/scale
    hipLaunchKernelGGL(layer_out_fin_kernel, dim3(B_TOT), dim3(256), 0, stream,
                       AapB, Hmk, QT, Ps_out, coefB, biasO, Vhat, out);
}

// Round 11
// 96.337 us; speedup vs baseline: 1.1853x; 1.1853x over previous
//
#include <hip/hip_runtime.h>

#define B_TOT 1024   // BATCH * nbr = 64 * 16
#define L_DIM 64
#define K_DIM 32
#define OUT_K 32
#define EPS_BN 1e-5f

typedef __attribute__((ext_vector_type(8))) short short8;
typedef __attribute__((ext_vector_type(4))) float f32x4;

__device__ __forceinline__ float reduce64(float v) {
    #pragma unroll
    for (int w = 1; w < 64; w <<= 1) v += __shfl_xor(v, w);
    return v;
}

__device__ __forceinline__ unsigned short f2bf(float x) {
    unsigned int u = __float_as_uint(x);
    u += 0x7FFF + ((u >> 16) & 1);   // RNE
    return (unsigned short)(u >> 16);
}

// ---------------------------------------------------------------------------
// hmeans + fused layer-0 stats (A0 never materialized).
// ---------------------------------------------------------------------------
__global__ __launch_bounds__(256, 4) void hmeans_l0_kernel(
    const float* __restrict__ Hr, const float* __restrict__ Hi,
    float* __restrict__ Hmk, float* __restrict__ Hml,
    const float* __restrict__ P0,   // layer0: P1a | P1u
    float* __restrict__ muS, float* __restrict__ muQ) {
    __shared__ float tile[64 * 132];
    __shared__ float hmkS[512];  // [c][l]
    __shared__ float hmlS[256];  // [c][k]
    int b = blockIdx.x;
    int tid = threadIdx.x;
    for (int ri = 0; ri < 2; ++ri) {
        const float* src = (ri == 0 ? Hr : Hi) + (size_t)b * 8192;
        const float4* src4 = (const float4*)src;
        for (int j = tid; j < 2048; j += 256) {
            float4 v = src4[j];
            int l = j >> 5, w0 = (j & 31) * 4;
            float* d = &tile[l * 132 + w0];
            d[0] = v.x; d[1] = v.y; d[2] = v.z; d[3] = v.w;
        }
        __syncthreads();
        {
            int l = tid >> 2, u = tid & 3;
            float s = 0.f;
            #pragma unroll
            for (int kk = 0; kk < 32; ++kk) s += tile[l * 132 + kk * 4 + u];
            s *= (1.0f / 32.0f);
            Hmk[(size_t)b * 512 + (ri * 4 + u) * 64 + l] = s;
            hmkS[(ri * 4 + u) * 64 + l] = s;
        }
        if (tid < 128) {
            int kk = tid >> 2, u = tid & 3;
            float s = 0.f;
            #pragma unroll
            for (int l = 0; l < 64; ++l) s += tile[l * 132 + kk * 4 + u];
            s *= (1.0f / 64.0f);
            Hml[(size_t)b * 256 + (ri * 4 + u) * 32 + kk] = s;
            hmlS[(ri * 4 + u) * 32 + kk] = s;
        }
        __syncthreads();
    }

    int wid = tid >> 6, lane = tid & 63;
    int o0 = __builtin_amdgcn_readfirstlane(wid << 4);
    float hmk[8], hml[8];
    #pragma unroll
    for (int c = 0; c < 8; ++c) hmk[c] = hmkS[c * 64 + lane];
    #pragma unroll
    for (int c = 0; c < 8; ++c) hml[c] = hmlS[c * 32 + (lane & 31)];

    for (int h = 0; h < 2; ++h) {
        float vs[8], qs[8];
        #pragma unroll
        for (int mm = 0; mm < 8; ++mm) {
            int o = o0 + h * 8 + mm;
            float4 p0 = *(const float4*)(P0 + o * 8);
            float4 p1 = *(const float4*)(P0 + o * 8 + 4);
            float pa = p0.x * hmk[0] + p0.y * hmk[1] + p0.z * hmk[2] + p0.w * hmk[3]
                     + p1.x * hmk[4] + p1.y * hmk[5] + p1.z * hmk[6] + p1.w * hmk[7];
            float v = fmaxf(0.1f * pa, 0.f);
            vs[mm] = v; qs[mm] = v * v;
        }
        #pragma unroll
        for (int s = 1; s < 64; s <<= 1) {
            #pragma unroll
            for (int mm = 0; mm < 8; ++mm) {
                vs[mm] += __shfl_xor(vs[mm], s);
                qs[mm] += __shfl_xor(qs[mm], s);
            }
        }
        if (lane == 0) {
            #pragma unroll
            for (int mm = 0; mm < 8; ++mm) {
                muS[b * 128 + o0 + h * 8 + mm] = vs[mm];
                muQ[b * 128 + o0 + h * 8 + mm] = qs[mm];
            }
        }
    }
    for (int h = 0; h < 2; ++h) {
        float vs[8], qs[8];
        #pragma unroll
        for (int mm = 0; mm < 8; ++mm) {
            int o = o0 + h * 8 + mm;
            float4 p0 = *(const float4*)(P0 + 512 + o * 8);
            float4 p1 = *(const float4*)(P0 + 512 + o * 8 + 4);
            float pu = p0.x * hml[0] + p0.y * hml[1] + p0.z * hml[2] + p0.w * hml[3]
                     + p1.x * hml[4] + p1.y * hml[5] + p1.z * hml[6] + p1.w * hml[7];
            float v = fmaxf(0.1f * pu, 0.f);
            vs[mm] = v; qs[mm] = v * v;
        }
        #pragma unroll
        for (int s = 1; s < 64; s <<= 1) {
            #pragma unroll
            for (int mm = 0; mm < 8; ++mm) {
                vs[mm] += __shfl_xor(vs[mm], s);
                qs[mm] += __shfl_xor(qs[mm], s);
            }
        }
        if (lane == 0) {
            #pragma unroll
            for (int mm = 0; mm < 8; ++mm) {
                muS[b * 128 + 64 + o0 + h * 8 + mm] = vs[mm] * 0.5f;
                muQ[b * 128 + 64 + o0 + h * 8 + mm] = qs[mm] * 0.5f;
            }
        }
    }
}

// ---------------------------------------------------------------------------
// Weight prep: QTo (fp32 i-major 64x32 for layer_out) and bf16 MFMA A-operand
// packs for layer-1 (K augmented to 96: cols 0..63 = 2*Q1, 64..71 = 0.1*P1,
// 72..95 = 0). Fragment layout: element j of lane: m=lane%16,
// k=(lane/16)*8+j; pack index = ((kt*4+otile)*64+lane)*8+j.
// ---------------------------------------------------------------------------
__global__ __launch_bounds__(256) void prep_weights_kernel(
    const float* __restrict__ Qh1,  // layer-1 Q base (Q1a|Q2a|Q1u|Q2u)
    const float* __restrict__ P1h,  // layer-1 P base (P1a|P1u)
    const float* __restrict__ Qo,   // out-layer Q base
    float* __restrict__ QTo,
    unsigned short* __restrict__ Qpack_ap,
    unsigned short* __restrict__ Qpack_ue) {
    int t = threadIdx.x;
    for (int idx = t; idx < 2048; idx += 256) {
        int i = idx >> 5, o = idx & 31;
        QTo[idx] = Qo[o * 64 + i];
    }
    const float* Q1a = Qh1;
    const float* Q1u = Qh1 + 2 * 4096;
    const float* P1a = P1h;
    const float* P1u = P1h + 512;
    for (int idx = t; idx < 6144; idx += 256) {
        int j = idx & 7, lane = (idx >> 3) & 63, ot = (idx >> 9) & 3, kt = idx >> 11;
        int m = lane & 15, kloc = (lane >> 4) * 8 + j;
        int o = ot * 16 + m, k = kt * 32 + kloc;
        float va = 0.f, vu = 0.f;
        if (k < 64)      { va = 2.0f * Q1a[o * 64 + k]; vu = 2.0f * Q1u[o * 64 + k]; }
        else if (k < 72) { va = 0.1f * P1a[o * 8 + (k - 64)]; vu = 0.1f * P1u[o * 8 + (k - 64)]; }
        Qpack_ap[idx] = f2bf(va);
        Qpack_ue[idx] = f2bf(vu);
    }
}

// ---------------------------------------------------------------------------
// Hidden layer 1 via MFMA. One block per b (4 waves).
// LDS B-operand: Bap[l][0..63]=BN(A0_ap) bf16, [64..71]=Hmk, [72..95]=0;
//                Bue[k][..] likewise with Hml. Row stride 104 bf16.
// D = Qpack @ B (K=96, 3 mfma/tile) + C-init(biasIn). Wave w owns o-tile w:
// AP 4 l-tiles, UE 2 k-tiles. Epilogue: relu, store AP, stats via 16-lane
// butterflies -> muS/muQ raw sums.
// ---------------------------------------------------------------------------
__global__ __launch_bounds__(256, 2) void layer_hidden1_kernel(
    float* __restrict__ Aap_out,
    const float* __restrict__ Hmk, const float* __restrict__ Hml,
    const unsigned short* __restrict__ Qpack_ap,
    const unsigned short* __restrict__ Qpack_ue,
    const float* __restrict__ P0,     // layer0 P1a | P1u
    const float* __restrict__ coefA,  // scAP[64] shAP[64] scUE[64] shUE[64]
    const float* __restrict__ biasIn, // [b][128]
    float* __restrict__ muS, float* __restrict__ muQ) {
    __shared__ unsigned short Bap[64 * 104];
    __shared__ unsigned short Bue[32 * 104];
    int b = blockIdx.x, t = threadIdx.x;

    // ---- stage BN(A0_ap) ----
    {
        int l = t & 63, wid = t >> 6, i0 = wid << 4;
        float hmk[8];
        #pragma unroll
        for (int c = 0; c < 8; ++c) hmk[c] = Hmk[(size_t)b * 512 + c * 64 + l];
        unsigned short tmp[16];
        #pragma unroll
        for (int m = 0; m < 16; ++m) {
            int i = i0 + m;
            float4 p0 = *(const float4*)(P0 + i * 8);
            float4 p1 = *(const float4*)(P0 + i * 8 + 4);
            float pa = p0.x * hmk[0] + p0.y * hmk[1] + p0.z * hmk[2] + p0.w * hmk[3]
                     + p1.x * hmk[4] + p1.y * hmk[5] + p1.z * hmk[6] + p1.w * hmk[7];
            float a0 = fmaxf(0.1f * pa, 0.f);
            tmp[m] = f2bf(a0 * coefA[i] + coefA[64 + i]);
        }
        short8 s0, s1;
        #pragma unroll
        for (int j = 0; j < 8; ++j) { s0[j] = (short)tmp[j]; s1[j] = (short)tmp[8 + j]; }
        *(short8*)(&Bap[l * 104 + i0]) = s0;
        *(short8*)(&Bap[l * 104 + i0 + 8]) = s1;
        if (wid == 0) {
            #pragma unroll
            for (int c = 0; c < 8; ++c) Bap[l * 104 + 64 + c] = f2bf(hmk[c]);
            #pragma unroll
            for (int c = 72; c < 96; ++c) Bap[l * 104 + c] = 0;
        }
    }
    // ---- stage BN(A0_ue) ----
    {
        int k = t & 31, g = t >> 5, i0 = g << 3;
        float hml[8];
        #pragma unroll
        for (int c = 0; c < 8; ++c) hml[c] = Hml[(size_t)b * 256 + c * 32 + k];
        unsigned short tu[8];
        #pragma unroll
        for (int m = 0; m < 8; ++m) {
            int i = i0 + m;
            float4 p0 = *(const float4*)(P0 + 512 + i * 8);
            float4 p1 = *(const float4*)(P0 + 512 + i * 8 + 4);
            float pu = p0.x * hml[0] + p0.y * hml[1] + p0.z * hml[2] + p0.w * hml[3]
                     + p1.x * hml[4] + p1.y * hml[5] + p1.z * hml[6] + p1.w * hml[7];
            float a0 = fmaxf(0.1f * pu, 0.f);
            tu[m] = f2bf(a0 * coefA[128 + i] + coefA[192 + i]);
        }
        short8 s0;
        #pragma unroll
        for (int j = 0; j < 8; ++j) s0[j] = (short)tu[j];
        *(short8*)(&Bue[k * 104 + i0]) = s0;
        if (t < 32) {
            #pragma unroll
            for (int c = 0; c < 8; ++c) Bue[k * 104 + 64 + c] = f2bf(hml[c]);
            #pragma unroll
            for (int c = 72; c < 96; ++c) Bue[k * 104 + c] = 0;
        }
    }
    __syncthreads();

    // ---- MFMA ----
    int lane = t & 63, w = t >> 6;
    int m16 = lane & 15, g4 = lane >> 4;
    int obase = w * 16 + g4 * 4;

    short8 aq[3], aqu[3];
    #pragma unroll
    for (int kt = 0; kt < 3; ++kt) {
        aq[kt]  = *(const short8*)(Qpack_ap + (((kt * 4 + w) * 64 + lane) << 3));
        aqu[kt] = *(const short8*)(Qpack_ue + (((kt * 4 + w) * 64 + lane) << 3));
    }

    // AP: 4 l-tiles
    float vsum[4] = {0.f, 0.f, 0.f, 0.f}, vsq[4] = {0.f, 0.f, 0.f, 0.f};
    #pragma unroll
    for (int lt = 0; lt < 4; ++lt) {
        f32x4 acc = *(const f32x4*)(biasIn + b * 128 + obase);
        #pragma unroll
        for (int kt = 0; kt < 3; ++kt) {
            short8 bf = *(const short8*)(&Bap[(lt * 16 + m16) * 104 + kt * 32 + g4 * 8]);
            acc = __builtin_amdgcn_mfma_f32_16x16x32_bf16(aq[kt], bf, acc, 0, 0, 0);
        }
        int lsp = lt * 16 + m16;
        #pragma unroll
        for (int r = 0; r < 4; ++r) {
            float v = fmaxf(acc[r], 0.f);
            Aap_out[(size_t)b * 4096 + (obase + r) * 64 + lsp] = v;
            vsum[r] += v; vsq[r] += v * v;
        }
    }
    #pragma unroll
    for (int s = 1; s < 16; s <<= 1) {
        #pragma unroll
        for (int r = 0; r < 4; ++r) {
            vsum[r] += __shfl_xor(vsum[r], s);
            vsq[r]  += __shfl_xor(vsq[r], s);
        }
    }
    if (m16 == 0) {
        #pragma unroll
        for (int r = 0; r < 4; ++r) {
            muS[b * 128 + obase + r] = vsum[r];
            muQ[b * 128 + obase + r] = vsq[r];
        }
    }

    // UE: 2 k-spatial tiles (no global store needed)
    float usum[4] = {0.f, 0.f, 0.f, 0.f}, usq[4] = {0.f, 0.f, 0.f, 0.f};
    #pragma unroll
    for (int nt = 0; nt < 2; ++nt) {
        f32x4 acc = *(const f32x4*)(biasIn + b * 128 + 64 + obase);
        #pragma unroll
        for (int kt = 0; kt < 3; ++kt) {
            short8 bf = *(const short8*)(&Bue[(nt * 16 + m16) * 104 + kt * 32 + g4 * 8]);
            acc = __builtin_amdgcn_mfma_f32_16x16x32_bf16(aqu[kt], bf, acc, 0, 0, 0);
        }
        #pragma unroll
        for (int r = 0; r < 4; ++r) {
            float v = fmaxf(acc[r], 0.f);
            usum[r] += v; usq[r] += v * v;
        }
    }
    #pragma unroll
    for (int s = 1; s < 16; s <<= 1) {
        #pragma unroll
        for (int r = 0; r < 4; ++r) {
            usum[r] += __shfl_xor(usum[r], s);
            usq[r]  += __shfl_xor(usq[r], s);
        }
    }
    if (m16 == 0) {
        #pragma unroll
        for (int r = 0; r < 4; ++r) {
            muS[b * 128 + 64 + obase + r] = usum[r];
            muQ[b * 128 + 64 + obase + r] = usq[r];
        }
    }
}

// ---------------------------------------------------------------------------
__global__ __launch_bounds__(256, 8) void bn_finalize_kernel(
    const float* __restrict__ muS, const float* __restrict__ muQ,
    const float* __restrict__ gamma, const float* __restrict__ beta,
    float* __restrict__ coef) {
    __shared__ float redS[4], redQ[4];
    int ch = blockIdx.x;
    int tid = threadIdx.x;
    float s = 0.f, q = 0.f;
    for (int j = tid; j < 1024; j += 256) {
        s += muS[j * 128 + ch];
        q += muQ[j * 128 + ch];
    }
    s = reduce64(s);
    q = reduce64(q);
    int wave = tid >> 6, lane = tid & 63;
    if (lane == 0) { redS[wave] = s; redQ[wave] = q; }
    __syncthreads();
    if (tid == 0) {
        s = redS[0] + redS[1] + redS[2] + redS[3];
        q = redQ[0] + redQ[1] + redQ[2] + redQ[3];
        bool ap = ch < 64;
        int o = ap ? ch : ch - 64;
        float cnt = ap ? (float)(B_TOT * L_DIM) : (float)(B_TOT * K_DIM);
        float m = s / cnt;
        float var = q / cnt - m * m;
        float sc = gamma[o] / sqrtf(var + EPS_BN);
        if (ap) { coef[o] = sc;       coef[64 + o] = beta[o] - m * sc; }
        else    { coef[128 + o] = sc; coef[192 + o] = beta[o] - m * sc; }
    }
}

// ---------------------------------------------------------------------------
__global__ __launch_bounds__(128, 8) void bias_hidden_kernel(
    const float* __restrict__ Q, const float* __restrict__ coef,
    const float* __restrict__ muS, float* __restrict__ bias) {
    __shared__ float mubn[128];
    int b = blockIdx.x, t = threadIdx.x;
    float raw = muS[b * 128 + t];
    if (t < 64) mubn[t] = raw * (1.0f / 64.0f) * coef[t] + coef[64 + t];
    else        mubn[t] = raw * (1.0f / 32.0f) * coef[64 + t] + coef[128 + t];
    __syncthreads();
    const float* Qm = (t < 64) ? (Q + 4096) : (Q + 3 * 4096);
    const float* mu = (t < 64) ? (mubn + 64) : mubn;
    int o = t & 63;
    const float4* Qrow = (const float4*)(Qm + o * 64);
    float sa = 0.f, sb = 0.f, sc2 = 0.f, sd = 0.f;
    #pragma unroll
    for (int j = 0; j < 16; ++j) {
        float4 q = Qrow[j];
        sa += q.x * mu[4 * j];
        sb += q.y * mu[4 * j + 1];
        sc2 += q.z * mu[4 * j + 2];
        sd += q.w * mu[4 * j + 3];
    }
    bias[b * 128 + t] = 2.f * ((sa + sb) + (sc2 + sd));
}

// ---------------------------------------------------------------------------
__global__ __launch_bounds__(64, 8) void bias_out_kernel(
    const float* __restrict__ Qo, const float* __restrict__ coef,
    const float* __restrict__ muS, float* __restrict__ biasO) {
    __shared__ float mubn[64];
    int b = blockIdx.x, t = threadIdx.x;
    mubn[t] = muS[b * 128 + 64 + t] * (1.0f / 32.0f) * coef[128 + t] + coef[192 + t];
    __syncthreads();
    if (t < 32) {
        const float4* Qrow = (const float4*)(Qo + OUT_K * 64 + t * 64);
        float sa = 0.f, sb = 0.f, sc2 = 0.f, sd = 0.f;
        #pragma unroll
        for (int j = 0; j < 16; ++j) {
            float4 q = Qrow[j];
            sa += q.x * mubn[4 * j];
            sb += q.y * mubn[4 * j + 1];
            sc2 += q.z * mubn[4 * j + 2];
            sd += q.w * mubn[4 * j + 3];
        }
        biasO[b * 32 + t] = 2.f * ((sa + sb) + (sc2 + sd));
    }
}

// ---------------------------------------------------------------------------
// Output layer fused with normalization/scale (i-major vector GEMM; this
// kernel is at its memory roofline: Aap 16MB + Vhat 32MB + out 32MB).
// ---------------------------------------------------------------------------
__global__ __launch_bounds__(256, 4) void layer_out_fin_kernel(
    const float* __restrict__ Aap_in,
    const float* __restrict__ Hmk,
    const float* __restrict__ QTo,
    const float* __restrict__ Po,
    const float* __restrict__ coefIn,
    const float* __restrict__ biasO,
    const float* __restrict__ Vhat,
    float* __restrict__ out) {
    __shared__ float sV[32 * 65];
    __shared__ float inv[32];
    int b = blockIdx.x, tid = threadIdx.x;
    int wid = tid >> 6, lane = tid & 63;
    int ob = __builtin_amdgcn_readfirstlane(wid << 3);

    float hmk[8];
    #pragma unroll
    for (int c = 0; c < 8; ++c) hmk[c] = Hmk[(size_t)b * 512 + c * 64 + lane];

    float bp[8];
    #pragma unroll
    for (int m = 0; m < 8; ++m) {
        int o = ob + m;
        float4 p0 = *(const float4*)(Po + o * 8);
        float4 p1 = *(const float4*)(Po + o * 8 + 4);
        float pa = p0.x * hmk[0] + p0.y * hmk[1] + p0.z * hmk[2] + p0.w * hmk[3]
                 + p1.x * hmk[4] + p1.y * hmk[5] + p1.z * hmk[6] + p1.w * hmk[7];
        bp[m] = 0.1f * pa + biasO[b * 32 + o];
    }

    float acc[8];
    #pragma unroll
    for (int m = 0; m < 8; ++m) acc[m] = 0.f;
    {
        const float* A_in = Aap_in + (size_t)b * 4096 + lane;
        #pragma unroll 4
        for (int i = 0; i < 64; ++i) {
            float x = A_in[i * 64];
            float aa = x * coefIn[i] + coefIn[64 + i];
            float4 q0 = *(const float4*)(QTo + i * 32 + ob);
            float4 q1 = *(const float4*)(QTo + i * 32 + ob + 4);
            acc[0] += q0.x * aa; acc[1] += q0.y * aa;
            acc[2] += q0.z * aa; acc[3] += q0.w * aa;
            acc[4] += q1.x * aa; acc[5] += q1.y * aa;
            acc[6] += q1.z * aa; acc[7] += q1.w * aa;
        }
    }
    #pragma unroll
    for (int m = 0; m < 8; ++m)
        sV[(ob + m) * 65 + lane] = 2.f * acc[m] + bp[m];

    __syncthreads();
    if (tid < 32) {
        float s = 0.f;
        #pragma unroll
        for (int l = 0; l < 64; ++l) { float x = sV[tid * 65 + l]; s += x * x; }
        inv[tid] = 8.0f / sqrtf(s);
    }
    __syncthreads();
    const float4* vh4 = (const float4*)(Vhat + (size_t)b * 8192);
    float4* o4 = (float4*)out + (size_t)b * 2048;
    for (int j = tid; j < 2048; j += 256) {
        int l = j >> 5, kk = j & 31;
        float p = sV[kk * 65 + l] * inv[kk];
        float4 x = vh4[j];
        x.x *= p; x.y *= p; x.z *= p; x.w *= p;
        o4[j] = x;
    }
}

// ---------------------------------------------------------------------------
extern "C" void kernel_launch(void* const* d_in, const int* in_sizes, int n_in,
                              void* d_out, int out_size, void* d_ws, size_t ws_size,
                              hipStream_t stream) {
    const float* Hr        = (const float*)d_in[0];
    const float* Hi        = (const float*)d_in[1];
    const float* Vhat      = (const float*)d_in[2];
    const float* Qs_hidden = (const float*)d_in[3];
    const float* Ps_hidden = (const float*)d_in[4];
    const float* Qs_out    = (const float*)d_in[5];
    const float* Ps_out    = (const float*)d_in[6];
    const float* bn_gamma  = (const float*)d_in[7];
    const float* bn_beta   = (const float*)d_in[8];
    float* out = (float*)d_out;

    float* ws    = (float*)d_ws;
    float* Hmk   = ws;                    // 1024*512
    float* Hml   = Hmk + 524288;          // 1024*256
    float* AapB  = Hml + 262144;          // 1024*4096
    float* muS   = AapB + 4194304;        // 1024*128
    float* muQ   = muS + 131072;          // 1024*128
    float* coefA = muQ + 131072;          // 256
    float* coefB = coefA + 256;           // 256
    float* biasA = coefB + 256;           // 1024*128
    float* biasO = biasA + 131072;        // 1024*32
    float* QTo   = biasO + 32768;         // 2048
    unsigned short* Qpack_ap = (unsigned short*)(QTo + 2048);  // 6144 ushort
    unsigned short* Qpack_ue = Qpack_ap + 6144;                // 6144 ushort

    // weight prep (reads inputs only)
    hipLaunchKernelGGL(prep_weights_kernel, dim3(1), dim3(256), 0, stream,
                       Qs_hidden + 4 * 4096, Ps_hidden + 2 * 512, Qs_out,
                       QTo, Qpack_ap, Qpack_ue);

    // hmeans + layer-0 stats
    hipLaunchKernelGGL(hmeans_l0_kernel, dim3(B_TOT), dim3(256), 0, stream,
                       Hr, Hi, Hmk, Hml, Ps_hidden, muS, muQ);
    hipLaunchKernelGGL(bn_finalize_kernel, dim3(128), dim3(256), 0, stream,
                       muS, muQ, bn_gamma, bn_beta, coefA);
    hipLaunchKernelGGL(bias_hidden_kernel, dim3(B_TOT), dim3(128), 0, stream,
                       Qs_hidden + 4 * 4096, coefA, muS, biasA);

    // hidden layer 1: MFMA (one block per b)
    hipLaunchKernelGGL(layer_hidden1_kernel, dim3(B_TOT), dim3(256), 0, stream,
                       AapB, Hmk, Hml, Qpack_ap, Qpack_ue,
                       Ps_hidden, coefA, biasA, muS, muQ);
    hipLaunchKernelGGL(bn_finalize_kernel, dim3(128), dim3(256), 0, stream,
                       muS, muQ, bn_gamma + 64, bn_beta + 64, coefB);
    hipLaunchKernelGGL(bias_out_kernel, dim3(B_TOT), dim3(64), 0, stream,
                       Qs_out, coefB, muS, biasO);

    // output layer fused with normalization/scale
    hipLaunchKernelGGL(layer_out_fin_kernel, dim3(B_TOT), dim3(256), 0, stream,
                       AapB, Hmk, QTo, Ps_out, coefB, biasO, Vhat, out);
}